// Round 12
// baseline (1799.840 us; speedup 1.0000x reference)
//
#include <hip/hip_runtime.h>
#include <float.h>

// Sparsemax attention v6: wave-independent streaming remat, zero barriers.
// B=2,H=16,S=2048,D=64 fp32, temperature 8.
//
// prep: K -> fp16 (ws), V -> fp16 TRANSPOSED VT[bh][64][2048] (ws).
// main: block = 256 thr = 4 INDEPENDENT waves; each wave owns 16 q-rows x
//   all 2048 kcols of one (b,h). Per wave, 3 streaming scans with the score
//   tile rematerialized per 16 cols (transient f32x4 -> no reg blowup):
//     scan 1: row max (lane-local + shfl_xor 16/32);
//     scan 2: collect {s > max-8} into per-lane LDS slots (cap 12, determin.);
//     Michelot on lists fully in-wave (static reads, shfl reduce, ~4 iters);
//       overflow -> wave-local full-scan fallback (never hit for Gaussian);
//     scan 3: PV: p=max(s-tau,0) packed fp16, round-10 shuffle-transpose into
//       B-frags, A = VT rows, accumulate pv[4] over all 64 chunks.
//   Output written directly (float4), no split-K, no __syncthreads anywhere.

#define S_LEN 2048
#define DHEAD 64
#define WROWS 16
#define BWAVES 4
#define LCAP 12
#define FB_ITERS 12

typedef _Float16 f16x8 __attribute__((ext_vector_type(8)));
typedef __attribute__((ext_vector_type(4))) float f32x4;
typedef __attribute__((ext_vector_type(8))) unsigned short u16x8;

__device__ __forceinline__ unsigned short f2h(float x) {
    return __builtin_bit_cast(unsigned short, (_Float16)x);
}
__device__ __forceinline__ unsigned int pk2h(float lo, float hi) {
    return (unsigned int)f2h(lo) | ((unsigned int)f2h(hi) << 16);
}
__device__ __forceinline__ f16x8 cvt8h(float4 a, float4 b) {
    union { unsigned int u[4]; f16x8 v; } r;
    r.u[0] = pk2h(a.x, a.y); r.u[1] = pk2h(a.z, a.w);
    r.u[2] = pk2h(b.x, b.y); r.u[3] = pk2h(b.z, b.w);
    return r.v;
}

__global__ __launch_bounds__(256)
void cvt_f16_kernel(const float* __restrict__ src, uint4* __restrict__ dst, int n8) {
    int i = blockIdx.x * 256 + threadIdx.x;
    if (i >= n8) return;
    const float4* s4 = reinterpret_cast<const float4*>(src);
    float4 a = s4[2 * i], b = s4[2 * i + 1];
    uint4 o;
    o.x = pk2h(a.x, a.y); o.y = pk2h(a.z, a.w);
    o.z = pk2h(b.x, b.y); o.w = pk2h(b.z, b.w);
    dst[i] = o;
}

// V[bh][2048][64] fp32 -> VT[bh][64][2048] fp16, 64x64 tiles via LDS
__global__ __launch_bounds__(256)
void vt_kernel(const float* __restrict__ V, unsigned short* __restrict__ VT) {
    __shared__ unsigned short tile[64][72];   // +8 pad
    const int t  = threadIdx.x;
    const int bh = blockIdx.x >> 5;           // 32 s-tiles per bh
    const int s0 = (blockIdx.x & 31) * 64;
    const float* Vb = V + ((size_t)bh * S_LEN + s0) * DHEAD;
    const int r = t >> 2, q = t & 3;
    #pragma unroll
    for (int j = 0; j < 4; ++j) {
        float4 v4 = *reinterpret_cast<const float4*>(Vb + (size_t)r * DHEAD + q * 16 + j * 4);
        tile[r][q * 16 + j * 4 + 0] = f2h(v4.x);
        tile[r][q * 16 + j * 4 + 1] = f2h(v4.y);
        tile[r][q * 16 + j * 4 + 2] = f2h(v4.z);
        tile[r][q * 16 + j * 4 + 3] = f2h(v4.w);
    }
    __syncthreads();
    const int d = t >> 2;
    union { unsigned short s[16]; u16x8 v[2]; } o;
    #pragma unroll
    for (int i = 0; i < 16; ++i) o.s[i] = tile[q * 16 + i][d];
    u16x8* dst = reinterpret_cast<u16x8*>(VT + ((size_t)bh * DHEAD + d) * S_LEN + s0 + q * 16);
    dst[0] = o.v[0];
    dst[1] = o.v[1];
}

__global__ __launch_bounds__(256, 6)
void spx_main(const float* __restrict__ Q,
              const unsigned short* __restrict__ Kh,
              const unsigned short* __restrict__ VT,
              float* __restrict__ O)
{
    __shared__ float s_lv[BWAVES * WROWS * 4 * LCAP];   // 12 KB, per-lane slots

    const int t    = threadIdx.x;
    const int widx = t >> 6;
    const int l    = t & 63;
    const int lm   = l & 15;
    const int lk   = l >> 4;

    int bid = blockIdx.x;
    if (((int)gridDim.x & 7) == 0)
        bid = (bid & 7) * ((int)gridDim.x >> 3) + (bid >> 3);   // XCD swizzle
    const int nrb   = S_LEN / (WROWS * BWAVES);      // 32 row-blocks per bh
    const int bh    = bid / nrb;
    const int row0w = (bid % nrb) * (WROWS * BWAVES) + widx * WROWS;

    const size_t bhoff = (size_t)bh * S_LEN * DHEAD;
    const float* Qf = Q + bhoff;
    const unsigned short* KhB = Kh + bhoff;
    const unsigned short* VTb = VT + bhoff;
    float* Of = O + bhoff;

    // ---- Q^T B-fragments: lane (lm,lk) = Q[row0w+lm][kp*32 + lk*8 + j] ----
    f16x8 qfrag[2];
    #pragma unroll
    for (int kp = 0; kp < 2; ++kp) {
        const float* qp = Qf + (size_t)(row0w + lm) * DHEAD + kp * 32 + lk * 8;
        qfrag[kp] = cvt8h(*reinterpret_cast<const float4*>(qp),
                          *reinterpret_cast<const float4*>(qp + 4));
    }

    // transient score tile: S[qrow=lm][c0_ + lk*4 + e], c0_ = 16-col base
    #define SCORE_TILE(a_, c0_)                                                  \
        {                                                                        \
            const unsigned short* kp8_ = KhB + (size_t)((c0_) + lm) * DHEAD;     \
            f16x8 k0_ = *reinterpret_cast<const f16x8*>(kp8_ + lk * 8);          \
            f16x8 k1_ = *reinterpret_cast<const f16x8*>(kp8_ + 32 + lk * 8);     \
            a_ = (f32x4){0.f, 0.f, 0.f, 0.f};                                    \
            a_ = __builtin_amdgcn_mfma_f32_16x16x32_f16(k0_, qfrag[0], a_, 0, 0, 0); \
            a_ = __builtin_amdgcn_mfma_f32_16x16x32_f16(k1_, qfrag[1], a_, 0, 0, 0); \
        }

    // ---- scan 1: row max ----
    float mx = -FLT_MAX;
    #pragma unroll 8
    for (int ct = 0; ct < S_LEN / 16; ++ct) {
        f32x4 a;
        SCORE_TILE(a, ct * 16);
        mx = fmaxf(mx, fmaxf(fmaxf(a[0], a[1]), fmaxf(a[2], a[3])));
    }
    mx = fmaxf(mx, __shfl_xor(mx, 16));
    mx = fmaxf(mx, __shfl_xor(mx, 32));

    // ---- scan 2: collect {s > mx-8} into per-lane LDS slots ----
    const float thr = mx - 8.f;
    const int base = ((widx * WROWS + lm) * 4 + lk) * LCAP;
    int own = 0;
    #pragma unroll 4
    for (int ct = 0; ct < S_LEN / 16; ++ct) {
        f32x4 a;
        SCORE_TILE(a, ct * 16);
        #pragma unroll
        for (int e = 0; e < 4; ++e) {
            const float v = a[e];
            if (v > thr) {
                if (own < LCAP) s_lv[base + own] = v;
                ++own;
            }
        }
    }

    // ---- tau: in-wave list Michelot (or wave-local full-scan fallback) ----
    float tauF;
    if (!__any(own > LCAP)) {
        float cand[LCAP];
        #pragma unroll
        for (int s = 0; s < LCAP; ++s)
            cand[s] = (s < own) ? s_lv[base + s] : -FLT_MAX;
        float tv = mx - 8.f;
        int cprev = -1;
        for (int it = 0; it < 16; ++it) {
            float s = 0.f, c = 0.f;
            #pragma unroll
            for (int q = 0; q < LCAP; ++q) {
                const bool in = cand[q] > tv;
                s += in ? cand[q] : 0.f;
                c += in ? 1.f : 0.f;
            }
            s += __shfl_xor(s, 16); c += __shfl_xor(c, 16);
            s += __shfl_xor(s, 32); c += __shfl_xor(c, 32);
            tv = (s - 8.f) / c;
            const int C = (int)c;
            const bool done = (C == cprev);
            cprev = C;
            if (__all(done ? 1 : 0)) break;   // all 16 rows at fixpoint: exact
        }
        tauF = tv;
    } else {
        // full-scan Michelot with rematerialized scores (wave-local)
        float tv = mx - 8.f;
        for (int it = 0; it < FB_ITERS; ++it) {
            float s = 0.f, c = 0.f;
            #pragma unroll 4
            for (int ct = 0; ct < S_LEN / 16; ++ct) {
                f32x4 a;
                SCORE_TILE(a, ct * 16);
                #pragma unroll
                for (int e = 0; e < 4; ++e) {
                    const bool in = a[e] > tv;
                    s += in ? a[e] : 0.f;
                    c += in ? 1.f : 0.f;
                }
            }
            s += __shfl_xor(s, 16); c += __shfl_xor(c, 16);
            s += __shfl_xor(s, 32); c += __shfl_xor(c, 32);
            tv = (s - 8.f) / c;
        }
        tauF = tv;
    }

    // ---- scan 3: PV; pack p -> fp16, shuffle-transpose -> B-frag, MFMA ----
    f32x4 pv[4];
    #pragma unroll
    for (int d0 = 0; d0 < 4; ++d0) pv[d0] = (f32x4){0.f, 0.f, 0.f, 0.f};

    const int srcA = lm + 32 * (lk & 1);     // lane holding kcols (lk&1)*8+0..3
    const int srcB = srcA + 16;              // +4..7
    const bool hiCt = (lk >> 1) != 0;        // this lane's chunk-half

    #pragma unroll 2
    for (int ch = 0; ch < S_LEN / 32; ++ch) {
        f32x4 aA, aB;
        SCORE_TILE(aA, ch * 32);
        SCORE_TILE(aB, ch * 32 + 16);
        const unsigned int pA0 = pk2h(fmaxf(aA[0] - tauF, 0.f), fmaxf(aA[1] - tauF, 0.f));
        const unsigned int pA1 = pk2h(fmaxf(aA[2] - tauF, 0.f), fmaxf(aA[3] - tauF, 0.f));
        const unsigned int pB0 = pk2h(fmaxf(aB[0] - tauF, 0.f), fmaxf(aB[1] - tauF, 0.f));
        const unsigned int pB1 = pk2h(fmaxf(aB[2] - tauF, 0.f), fmaxf(aB[3] - tauF, 0.f));
        const unsigned int xA0 = (unsigned int)__shfl((int)pA0, srcA);
        const unsigned int xB0 = (unsigned int)__shfl((int)pB0, srcA);
        const unsigned int xA1 = (unsigned int)__shfl((int)pA1, srcA);
        const unsigned int xB1 = (unsigned int)__shfl((int)pB1, srcA);
        const unsigned int yA0 = (unsigned int)__shfl((int)pA0, srcB);
        const unsigned int yB0 = (unsigned int)__shfl((int)pB0, srcB);
        const unsigned int yA1 = (unsigned int)__shfl((int)pA1, srcB);
        const unsigned int yB1 = (unsigned int)__shfl((int)pB1, srcB);
        union { unsigned int u[4]; f16x8 v; } pf;
        pf.u[0] = hiCt ? xB0 : xA0;
        pf.u[1] = hiCt ? xB1 : xA1;
        pf.u[2] = hiCt ? yB0 : yA0;
        pf.u[3] = hiCt ? yB1 : yA1;
        #pragma unroll
        for (int d0 = 0; d0 < 4; ++d0) {
            const unsigned short* vp = VTb + (size_t)(d0 * 16 + lm) * S_LEN
                                           + ch * 32 + lk * 8;
            f16x8 vfrag = *reinterpret_cast<const f16x8*>(vp);
            pv[d0] = __builtin_amdgcn_mfma_f32_16x16x32_f16(vfrag, pf.v, pv[d0], 0, 0, 0);
        }
    }

    // ---- write O: pv[d0][e] = O^T[dim=d0*16+lk*4+e][qrow=lm] ----
    #pragma unroll
    for (int d0 = 0; d0 < 4; ++d0) {
        float4 o;
        o.x = pv[d0][0] * 0.125f;
        o.y = pv[d0][1] * 0.125f;
        o.z = pv[d0][2] * 0.125f;
        o.w = pv[d0][3] * 0.125f;
        *reinterpret_cast<float4*>(Of + (size_t)(row0w + lm) * DHEAD + d0 * 16 + lk * 4) = o;
    }
    #undef SCORE_TILE
}

extern "C" void kernel_launch(void* const* d_in, const int* in_sizes, int n_in,
                              void* d_out, int out_size, void* d_ws, size_t ws_size,
                              hipStream_t stream) {
    const float* q = (const float*)d_in[0];
    const float* k = (const float*)d_in[1];
    const float* v = (const float*)d_in[2];
    float* out = (float*)d_out;

    const int nElem = in_sizes[0];                    // B*H*S*D
    const int BH    = nElem / (S_LEN * DHEAD);

    unsigned short* kh = (unsigned short*)d_ws;
    unsigned short* vt = kh + nElem;

    const int n8 = nElem / 8;
    cvt_f16_kernel<<<(n8 + 255) / 256, 256, 0, stream>>>(k, (uint4*)kh, n8);
    vt_kernel<<<BH * (S_LEN / 64), 256, 0, stream>>>(v, vt);
    const int grid = BH * (S_LEN / (WROWS * BWAVES));  // 1024 blocks
    spx_main<<<grid, 256, 0, stream>>>(q, kh, vt, out);
}

// Round 13
// 1786.783 us; speedup vs baseline: 1.0073x; 1.0073x over previous
//
#include <hip/hip_runtime.h>
#include <float.h>

// Sparsemax attention v6b: wave-independent streaming remat, zero barriers.
// = round 12 EXACTLY, with the one broken knob fixed: __launch_bounds__(256,4)
//   instead of (256,6). r12's (256,6) starved the kernel to 36 VGPRs ->
//   AGPR<->VGPR shuttle bloat (3x VALU) + no load pipelining -> 1800 us.
//   128-VGPR budget = 4 waves/SIMD, room for qfrag + pv + pipelined loads.

#define S_LEN 2048
#define DHEAD 64
#define WROWS 16
#define BWAVES 4
#define LCAP 12
#define FB_ITERS 12

typedef _Float16 f16x8 __attribute__((ext_vector_type(8)));
typedef __attribute__((ext_vector_type(4))) float f32x4;
typedef __attribute__((ext_vector_type(8))) unsigned short u16x8;

__device__ __forceinline__ unsigned short f2h(float x) {
    return __builtin_bit_cast(unsigned short, (_Float16)x);
}
__device__ __forceinline__ unsigned int pk2h(float lo, float hi) {
    return (unsigned int)f2h(lo) | ((unsigned int)f2h(hi) << 16);
}
__device__ __forceinline__ f16x8 cvt8h(float4 a, float4 b) {
    union { unsigned int u[4]; f16x8 v; } r;
    r.u[0] = pk2h(a.x, a.y); r.u[1] = pk2h(a.z, a.w);
    r.u[2] = pk2h(b.x, b.y); r.u[3] = pk2h(b.z, b.w);
    return r.v;
}

__global__ __launch_bounds__(256)
void cvt_f16_kernel(const float* __restrict__ src, uint4* __restrict__ dst, int n8) {
    int i = blockIdx.x * 256 + threadIdx.x;
    if (i >= n8) return;
    const float4* s4 = reinterpret_cast<const float4*>(src);
    float4 a = s4[2 * i], b = s4[2 * i + 1];
    uint4 o;
    o.x = pk2h(a.x, a.y); o.y = pk2h(a.z, a.w);
    o.z = pk2h(b.x, b.y); o.w = pk2h(b.z, b.w);
    dst[i] = o;
}

// V[bh][2048][64] fp32 -> VT[bh][64][2048] fp16, 64x64 tiles via LDS
__global__ __launch_bounds__(256)
void vt_kernel(const float* __restrict__ V, unsigned short* __restrict__ VT) {
    __shared__ unsigned short tile[64][72];   // +8 pad
    const int t  = threadIdx.x;
    const int bh = blockIdx.x >> 5;           // 32 s-tiles per bh
    const int s0 = (blockIdx.x & 31) * 64;
    const float* Vb = V + ((size_t)bh * S_LEN + s0) * DHEAD;
    const int r = t >> 2, q = t & 3;
    #pragma unroll
    for (int j = 0; j < 4; ++j) {
        float4 v4 = *reinterpret_cast<const float4*>(Vb + (size_t)r * DHEAD + q * 16 + j * 4);
        tile[r][q * 16 + j * 4 + 0] = f2h(v4.x);
        tile[r][q * 16 + j * 4 + 1] = f2h(v4.y);
        tile[r][q * 16 + j * 4 + 2] = f2h(v4.z);
        tile[r][q * 16 + j * 4 + 3] = f2h(v4.w);
    }
    __syncthreads();
    const int d = t >> 2;
    union { unsigned short s[16]; u16x8 v[2]; } o;
    #pragma unroll
    for (int i = 0; i < 16; ++i) o.s[i] = tile[q * 16 + i][d];
    u16x8* dst = reinterpret_cast<u16x8*>(VT + ((size_t)bh * DHEAD + d) * S_LEN + s0 + q * 16);
    dst[0] = o.v[0];
    dst[1] = o.v[1];
}

__global__ __launch_bounds__(256, 4)
void spx_main(const float* __restrict__ Q,
              const unsigned short* __restrict__ Kh,
              const unsigned short* __restrict__ VT,
              float* __restrict__ O)
{
    __shared__ float s_lv[BWAVES * WROWS * 4 * LCAP];   // 12 KB, per-lane slots

    const int t    = threadIdx.x;
    const int widx = t >> 6;
    const int l    = t & 63;
    const int lm   = l & 15;
    const int lk   = l >> 4;

    int bid = blockIdx.x;
    if (((int)gridDim.x & 7) == 0)
        bid = (bid & 7) * ((int)gridDim.x >> 3) + (bid >> 3);   // XCD swizzle
    const int nrb   = S_LEN / (WROWS * BWAVES);      // 32 row-blocks per bh
    const int bh    = bid / nrb;
    const int row0w = (bid % nrb) * (WROWS * BWAVES) + widx * WROWS;

    const size_t bhoff = (size_t)bh * S_LEN * DHEAD;
    const float* Qf = Q + bhoff;
    const unsigned short* KhB = Kh + bhoff;
    const unsigned short* VTb = VT + bhoff;
    float* Of = O + bhoff;

    // ---- Q^T B-fragments: lane (lm,lk) = Q[row0w+lm][kp*32 + lk*8 + j] ----
    f16x8 qfrag[2];
    #pragma unroll
    for (int kp = 0; kp < 2; ++kp) {
        const float* qp = Qf + (size_t)(row0w + lm) * DHEAD + kp * 32 + lk * 8;
        qfrag[kp] = cvt8h(*reinterpret_cast<const float4*>(qp),
                          *reinterpret_cast<const float4*>(qp + 4));
    }

    // transient score tile: S[qrow=lm][c0_ + lk*4 + e], c0_ = 16-col base
    #define SCORE_TILE(a_, c0_)                                                  \
        {                                                                        \
            const unsigned short* kp8_ = KhB + (size_t)((c0_) + lm) * DHEAD;     \
            f16x8 k0_ = *reinterpret_cast<const f16x8*>(kp8_ + lk * 8);          \
            f16x8 k1_ = *reinterpret_cast<const f16x8*>(kp8_ + 32 + lk * 8);     \
            a_ = (f32x4){0.f, 0.f, 0.f, 0.f};                                    \
            a_ = __builtin_amdgcn_mfma_f32_16x16x32_f16(k0_, qfrag[0], a_, 0, 0, 0); \
            a_ = __builtin_amdgcn_mfma_f32_16x16x32_f16(k1_, qfrag[1], a_, 0, 0, 0); \
        }

    // ---- scan 1: row max ----
    float mx = -FLT_MAX;
    #pragma unroll 8
    for (int ct = 0; ct < S_LEN / 16; ++ct) {
        f32x4 a;
        SCORE_TILE(a, ct * 16);
        mx = fmaxf(mx, fmaxf(fmaxf(a[0], a[1]), fmaxf(a[2], a[3])));
    }
    mx = fmaxf(mx, __shfl_xor(mx, 16));
    mx = fmaxf(mx, __shfl_xor(mx, 32));

    // ---- scan 2: collect {s > mx-8} into per-lane LDS slots ----
    const float thr = mx - 8.f;
    const int base = ((widx * WROWS + lm) * 4 + lk) * LCAP;
    int own = 0;
    #pragma unroll 4
    for (int ct = 0; ct < S_LEN / 16; ++ct) {
        f32x4 a;
        SCORE_TILE(a, ct * 16);
        #pragma unroll
        for (int e = 0; e < 4; ++e) {
            const float v = a[e];
            if (v > thr) {
                if (own < LCAP) s_lv[base + own] = v;
                ++own;
            }
        }
    }

    // ---- tau: in-wave list Michelot (or wave-local full-scan fallback) ----
    float tauF;
    if (!__any(own > LCAP)) {
        float cand[LCAP];
        #pragma unroll
        for (int s = 0; s < LCAP; ++s)
            cand[s] = (s < own) ? s_lv[base + s] : -FLT_MAX;
        float tv = mx - 8.f;
        int cprev = -1;
        for (int it = 0; it < 16; ++it) {
            float s = 0.f, c = 0.f;
            #pragma unroll
            for (int q = 0; q < LCAP; ++q) {
                const bool in = cand[q] > tv;
                s += in ? cand[q] : 0.f;
                c += in ? 1.f : 0.f;
            }
            s += __shfl_xor(s, 16); c += __shfl_xor(c, 16);
            s += __shfl_xor(s, 32); c += __shfl_xor(c, 32);
            tv = (s - 8.f) / c;
            const int C = (int)c;
            const bool done = (C == cprev);
            cprev = C;
            if (__all(done ? 1 : 0)) break;   // all 16 rows at fixpoint: exact
        }
        tauF = tv;
    } else {
        // full-scan Michelot with rematerialized scores (wave-local)
        float tv = mx - 8.f;
        for (int it = 0; it < FB_ITERS; ++it) {
            float s = 0.f, c = 0.f;
            #pragma unroll 4
            for (int ct = 0; ct < S_LEN / 16; ++ct) {
                f32x4 a;
                SCORE_TILE(a, ct * 16);
                #pragma unroll
                for (int e = 0; e < 4; ++e) {
                    const bool in = a[e] > tv;
                    s += in ? a[e] : 0.f;
                    c += in ? 1.f : 0.f;
                }
            }
            s += __shfl_xor(s, 16); c += __shfl_xor(c, 16);
            s += __shfl_xor(s, 32); c += __shfl_xor(c, 32);
            tv = (s - 8.f) / c;
        }
        tauF = tv;
    }

    // ---- scan 3: PV; pack p -> fp16, shuffle-transpose -> B-frag, MFMA ----
    f32x4 pv[4];
    #pragma unroll
    for (int d0 = 0; d0 < 4; ++d0) pv[d0] = (f32x4){0.f, 0.f, 0.f, 0.f};

    const int srcA = lm + 32 * (lk & 1);     // lane holding kcols (lk&1)*8+0..3
    const int srcB = srcA + 16;              // +4..7
    const bool hiCt = (lk >> 1) != 0;        // this lane's chunk-half

    #pragma unroll 2
    for (int ch = 0; ch < S_LEN / 32; ++ch) {
        f32x4 aA, aB;
        SCORE_TILE(aA, ch * 32);
        SCORE_TILE(aB, ch * 32 + 16);
        const unsigned int pA0 = pk2h(fmaxf(aA[0] - tauF, 0.f), fmaxf(aA[1] - tauF, 0.f));
        const unsigned int pA1 = pk2h(fmaxf(aA[2] - tauF, 0.f), fmaxf(aA[3] - tauF, 0.f));
        const unsigned int pB0 = pk2h(fmaxf(aB[0] - tauF, 0.f), fmaxf(aB[1] - tauF, 0.f));
        const unsigned int pB1 = pk2h(fmaxf(aB[2] - tauF, 0.f), fmaxf(aB[3] - tauF, 0.f));
        const unsigned int xA0 = (unsigned int)__shfl((int)pA0, srcA);
        const unsigned int xB0 = (unsigned int)__shfl((int)pB0, srcA);
        const unsigned int xA1 = (unsigned int)__shfl((int)pA1, srcA);
        const unsigned int xB1 = (unsigned int)__shfl((int)pB1, srcA);
        const unsigned int yA0 = (unsigned int)__shfl((int)pA0, srcB);
        const unsigned int yB0 = (unsigned int)__shfl((int)pB0, srcB);
        const unsigned int yA1 = (unsigned int)__shfl((int)pA1, srcB);
        const unsigned int yB1 = (unsigned int)__shfl((int)pB1, srcB);
        union { unsigned int u[4]; f16x8 v; } pf;
        pf.u[0] = hiCt ? xB0 : xA0;
        pf.u[1] = hiCt ? xB1 : xA1;
        pf.u[2] = hiCt ? yB0 : yA0;
        pf.u[3] = hiCt ? yB1 : yA1;
        #pragma unroll
        for (int d0 = 0; d0 < 4; ++d0) {
            const unsigned short* vp = VTb + (size_t)(d0 * 16 + lm) * S_LEN
                                           + ch * 32 + lk * 8;
            f16x8 vfrag = *reinterpret_cast<const f16x8*>(vp);
            pv[d0] = __builtin_amdgcn_mfma_f32_16x16x32_f16(vfrag, pf.v, pv[d0], 0, 0, 0);
        }
    }

    // ---- write O: pv[d0][e] = O^T[dim=d0*16+lk*4+e][qrow=lm] ----
    #pragma unroll
    for (int d0 = 0; d0 < 4; ++d0) {
        float4 o;
        o.x = pv[d0][0] * 0.125f;
        o.y = pv[d0][1] * 0.125f;
        o.z = pv[d0][2] * 0.125f;
        o.w = pv[d0][3] * 0.125f;
        *reinterpret_cast<float4*>(Of + (size_t)(row0w + lm) * DHEAD + d0 * 16 + lk * 4) = o;
    }
    #undef SCORE_TILE
}

extern "C" void kernel_launch(void* const* d_in, const int* in_sizes, int n_in,
                              void* d_out, int out_size, void* d_ws, size_t ws_size,
                              hipStream_t stream) {
    const float* q = (const float*)d_in[0];
    const float* k = (const float*)d_in[1];
    const float* v = (const float*)d_in[2];
    float* out = (float*)d_out;

    const int nElem = in_sizes[0];                    // B*H*S*D
    const int BH    = nElem / (S_LEN * DHEAD);

    unsigned short* kh = (unsigned short*)d_ws;
    unsigned short* vt = kh + nElem;

    const int n8 = nElem / 8;
    cvt_f16_kernel<<<(n8 + 255) / 256, 256, 0, stream>>>(k, (uint4*)kh, n8);
    vt_kernel<<<BH * (S_LEN / 64), 256, 0, stream>>>(v, vt);
    const int grid = BH * (S_LEN / (WROWS * BWAVES));  // 1024 blocks
    spx_main<<<grid, 256, 0, stream>>>(q, kh, vt, out);
}

// Round 14
// 536.456 us; speedup vs baseline: 3.3551x; 3.3307x over previous
//
#include <hip/hip_runtime.h>
#include <float.h>

// Sparsemax attention v6c: wave-independent streaming remat + FRAGMENT-
// CONTIGUOUS operand layouts.  B=2,H=16,S=2048,D=64 fp32, temperature 8.
//
// r12/r13 post-mortem: ~1024 vmem instr/wave, each a 16-segment gather
// (K rows stride 128B, VT rows stride 4KB) -> TA/L1 pipe saturation, wall
// invariant to occupancy/VGPR. Fix: prep kernels store K and V^T in MFMA
// fragment order so every load in the main kernel is base + lane*16B ->
// one contiguous 1KB per wave instruction.
//   Kswz[bh][tile=128][grp=2][lane=64][8]  : grp0 = k-dims 0..31, grp1 = 32..63
//   VTswz[bh][ch=64][d0=4][lane=64][8]     : PV B-fragments
// Main kernel logic byte-identical to r13 (3 streaming scans, per-lane LDS
// candidate slots, in-wave Michelot + full-scan fallback, PV shuffle-
// transpose, direct float4 output, zero barriers).

#define S_LEN 2048
#define DHEAD 64
#define WROWS 16
#define BWAVES 4
#define LCAP 12
#define FB_ITERS 12

typedef _Float16 f16x8 __attribute__((ext_vector_type(8)));
typedef __attribute__((ext_vector_type(4))) float f32x4;

__device__ __forceinline__ unsigned short f2h(float x) {
    return __builtin_bit_cast(unsigned short, (_Float16)x);
}
__device__ __forceinline__ unsigned int pk2h(float lo, float hi) {
    return (unsigned int)f2h(lo) | ((unsigned int)f2h(hi) << 16);
}
__device__ __forceinline__ f16x8 cvt8h(float4 a, float4 b) {
    union { unsigned int u[4]; f16x8 v; } r;
    r.u[0] = pk2h(a.x, a.y); r.u[1] = pk2h(a.z, a.w);
    r.u[2] = pk2h(b.x, b.y); r.u[3] = pk2h(b.z, b.w);
    return r.v;
}

// K fp32 [bh][2048][64] -> Kswz fragments. One thread = one 16B fragment.
// frag id: ((bh*128 + ct)*2 + grp)*64 + lane ; holds
//   f16(K[bh][ct*16 + (lane&15)][grp*32 + (lane>>4)*8 + 0..7])
__global__ __launch_bounds__(256)
void kswz_kernel(const float* __restrict__ K, uint4* __restrict__ dst, int nfrag) {
    int tid = blockIdx.x * 256 + threadIdx.x;
    if (tid >= nfrag) return;
    const int lane = tid & 63;
    const int grp  = (tid >> 6) & 1;
    const int ct   = (tid >> 7) & 127;
    const int bh   = tid >> 14;
    const int row  = ct * 16 + (lane & 15);
    const int col  = grp * 32 + (lane >> 4) * 8;
    const float* src = K + ((size_t)bh * S_LEN + row) * DHEAD + col;
    float4 a = *reinterpret_cast<const float4*>(src);
    float4 b = *reinterpret_cast<const float4*>(src + 4);
    uint4 o;
    o.x = pk2h(a.x, a.y); o.y = pk2h(a.z, a.w);
    o.z = pk2h(b.x, b.y); o.w = pk2h(b.z, b.w);
    dst[tid] = o;
}

// V fp32 [bh][2048][64] -> VTswz fragments. One thread = one 16B fragment.
// frag id: ((bh*64 + ch)*4 + d0)*64 + lane ; holds
//   f16(V[bh][ch*32 + (lane>>4)*8 + j][d0*16 + (lane&15)]), j=0..7
__global__ __launch_bounds__(256)
void vtswz_kernel(const float* __restrict__ V, uint4* __restrict__ dst, int nfrag) {
    int tid = blockIdx.x * 256 + threadIdx.x;
    if (tid >= nfrag) return;
    const int lane = tid & 63;
    const int d0   = (tid >> 6) & 3;
    const int ch   = (tid >> 8) & 63;
    const int bh   = tid >> 14;
    const int srow = ch * 32 + (lane >> 4) * 8;
    const int dcol = d0 * 16 + (lane & 15);
    const float* src = V + ((size_t)bh * S_LEN + srow) * DHEAD + dcol;
    unsigned int u[4];
    #pragma unroll
    for (int p = 0; p < 4; ++p)
        u[p] = pk2h(src[(2 * p) * DHEAD], src[(2 * p + 1) * DHEAD]);
    uint4 o; o.x = u[0]; o.y = u[1]; o.z = u[2]; o.w = u[3];
    dst[tid] = o;
}

__global__ __launch_bounds__(256, 4)
void spx_main(const float* __restrict__ Q,
              const unsigned short* __restrict__ Ks,
              const unsigned short* __restrict__ VTs,
              float* __restrict__ O)
{
    __shared__ float s_lv[BWAVES * WROWS * 4 * LCAP];   // 12 KB, per-lane slots

    const int t    = threadIdx.x;
    const int widx = t >> 6;
    const int l    = t & 63;
    const int lm   = l & 15;
    const int lk   = l >> 4;

    int bid = blockIdx.x;
    if (((int)gridDim.x & 7) == 0)
        bid = (bid & 7) * ((int)gridDim.x >> 3) + (bid >> 3);   // XCD swizzle
    const int nrb   = S_LEN / (WROWS * BWAVES);      // 32 row-blocks per bh
    const int bh    = bid / nrb;
    const int row0w = (bid % nrb) * (WROWS * BWAVES) + widx * WROWS;

    const float* Qf = Q + (size_t)bh * S_LEN * DHEAD;
    const unsigned short* KsB  = Ks  + (size_t)bh * S_LEN * DHEAD;  // 128 tiles * 1024
    const unsigned short* VTsB = VTs + (size_t)bh * S_LEN * DHEAD;  // 256 frag-groups * 512
    float* Of = O + (size_t)bh * S_LEN * DHEAD;

    // ---- Q^T B-fragments: lane (lm,lk) = Q[row0w+lm][kp*32 + lk*8 + j] ----
    f16x8 qfrag[2];
    #pragma unroll
    for (int kp = 0; kp < 2; ++kp) {
        const float* qp = Qf + (size_t)(row0w + lm) * DHEAD + kp * 32 + lk * 8;
        qfrag[kp] = cvt8h(*reinterpret_cast<const float4*>(qp),
                          *reinterpret_cast<const float4*>(qp + 4));
    }

    // transient score tile ct_ (16 cols): S[qrow=lm][ct_*16 + lk*4 + e]
    // loads are CONTIGUOUS: tile block = 1024 ushorts, lane fragment = l*8
    #define SCORE_TILE(a_, ct_)                                                  \
        {                                                                        \
            const unsigned short* kb_ = KsB + (size_t)(ct_) * 1024;              \
            f16x8 k0_ = *reinterpret_cast<const f16x8*>(kb_ + l * 8);            \
            f16x8 k1_ = *reinterpret_cast<const f16x8*>(kb_ + 512 + l * 8);      \
            a_ = (f32x4){0.f, 0.f, 0.f, 0.f};                                    \
            a_ = __builtin_amdgcn_mfma_f32_16x16x32_f16(k0_, qfrag[0], a_, 0, 0, 0); \
            a_ = __builtin_amdgcn_mfma_f32_16x16x32_f16(k1_, qfrag[1], a_, 0, 0, 0); \
        }

    // ---- scan 1: row max ----
    float mx = -FLT_MAX;
    #pragma unroll 8
    for (int ct = 0; ct < S_LEN / 16; ++ct) {
        f32x4 a;
        SCORE_TILE(a, ct);
        mx = fmaxf(mx, fmaxf(fmaxf(a[0], a[1]), fmaxf(a[2], a[3])));
    }
    mx = fmaxf(mx, __shfl_xor(mx, 16));
    mx = fmaxf(mx, __shfl_xor(mx, 32));

    // ---- scan 2: collect {s > mx-8} into per-lane LDS slots ----
    const float thr = mx - 8.f;
    const int base = ((widx * WROWS + lm) * 4 + lk) * LCAP;
    int own = 0;
    #pragma unroll 4
    for (int ct = 0; ct < S_LEN / 16; ++ct) {
        f32x4 a;
        SCORE_TILE(a, ct);
        #pragma unroll
        for (int e = 0; e < 4; ++e) {
            const float v = a[e];
            if (v > thr) {
                if (own < LCAP) s_lv[base + own] = v;
                ++own;
            }
        }
    }

    // ---- tau: in-wave list Michelot (or wave-local full-scan fallback) ----
    float tauF;
    if (!__any(own > LCAP)) {
        float cand[LCAP];
        #pragma unroll
        for (int s = 0; s < LCAP; ++s)
            cand[s] = (s < own) ? s_lv[base + s] : -FLT_MAX;
        float tv = mx - 8.f;
        int cprev = -1;
        for (int it = 0; it < 16; ++it) {
            float s = 0.f, c = 0.f;
            #pragma unroll
            for (int q = 0; q < LCAP; ++q) {
                const bool in = cand[q] > tv;
                s += in ? cand[q] : 0.f;
                c += in ? 1.f : 0.f;
            }
            s += __shfl_xor(s, 16); c += __shfl_xor(c, 16);
            s += __shfl_xor(s, 32); c += __shfl_xor(c, 32);
            tv = (s - 8.f) / c;
            const int C = (int)c;
            const bool done = (C == cprev);
            cprev = C;
            if (__all(done ? 1 : 0)) break;   // all 16 rows at fixpoint: exact
        }
        tauF = tv;
    } else {
        // full-scan Michelot with rematerialized scores (wave-local)
        float tv = mx - 8.f;
        for (int it = 0; it < FB_ITERS; ++it) {
            float s = 0.f, c = 0.f;
            #pragma unroll 4
            for (int ct = 0; ct < S_LEN / 16; ++ct) {
                f32x4 a;
                SCORE_TILE(a, ct);
                #pragma unroll
                for (int e = 0; e < 4; ++e) {
                    const bool in = a[e] > tv;
                    s += in ? a[e] : 0.f;
                    c += in ? 1.f : 0.f;
                }
            }
            s += __shfl_xor(s, 16); c += __shfl_xor(c, 16);
            s += __shfl_xor(s, 32); c += __shfl_xor(c, 32);
            tv = (s - 8.f) / c;
        }
        tauF = tv;
    }

    // ---- scan 3: PV; pack p -> fp16, shuffle-transpose -> B-frag, MFMA ----
    f32x4 pv[4];
    #pragma unroll
    for (int d0 = 0; d0 < 4; ++d0) pv[d0] = (f32x4){0.f, 0.f, 0.f, 0.f};

    const int srcA = lm + 32 * (lk & 1);     // lane holding kcols (lk&1)*8+0..3
    const int srcB = srcA + 16;              // +4..7
    const bool hiCt = (lk >> 1) != 0;        // this lane's chunk-half

    #pragma unroll 2
    for (int ch = 0; ch < S_LEN / 32; ++ch) {
        f32x4 aA, aB;
        SCORE_TILE(aA, 2 * ch);
        SCORE_TILE(aB, 2 * ch + 1);
        const unsigned int pA0 = pk2h(fmaxf(aA[0] - tauF, 0.f), fmaxf(aA[1] - tauF, 0.f));
        const unsigned int pA1 = pk2h(fmaxf(aA[2] - tauF, 0.f), fmaxf(aA[3] - tauF, 0.f));
        const unsigned int pB0 = pk2h(fmaxf(aB[0] - tauF, 0.f), fmaxf(aB[1] - tauF, 0.f));
        const unsigned int pB1 = pk2h(fmaxf(aB[2] - tauF, 0.f), fmaxf(aB[3] - tauF, 0.f));
        const unsigned int xA0 = (unsigned int)__shfl((int)pA0, srcA);
        const unsigned int xB0 = (unsigned int)__shfl((int)pB0, srcA);
        const unsigned int xA1 = (unsigned int)__shfl((int)pA1, srcA);
        const unsigned int xB1 = (unsigned int)__shfl((int)pB1, srcA);
        const unsigned int yA0 = (unsigned int)__shfl((int)pA0, srcB);
        const unsigned int yB0 = (unsigned int)__shfl((int)pB0, srcB);
        const unsigned int yA1 = (unsigned int)__shfl((int)pA1, srcB);
        const unsigned int yB1 = (unsigned int)__shfl((int)pB1, srcB);
        union { unsigned int u[4]; f16x8 v; } pf;
        pf.u[0] = hiCt ? xB0 : xA0;
        pf.u[1] = hiCt ? xB1 : xA1;
        pf.u[2] = hiCt ? yB0 : yA0;
        pf.u[3] = hiCt ? yB1 : yA1;
        #pragma unroll
        for (int d0 = 0; d0 < 4; ++d0) {
            // CONTIGUOUS fragment: group (ch*4 + d0), lane offset l*8
            const unsigned short* vp = VTsB + ((size_t)(ch * 4 + d0) << 9) + l * 8;
            f16x8 vfrag = *reinterpret_cast<const f16x8*>(vp);
            pv[d0] = __builtin_amdgcn_mfma_f32_16x16x32_f16(vfrag, pf.v, pv[d0], 0, 0, 0);
        }
    }

    // ---- write O: pv[d0][e] = O^T[dim=d0*16+lk*4+e][qrow=lm] ----
    #pragma unroll
    for (int d0 = 0; d0 < 4; ++d0) {
        float4 o;
        o.x = pv[d0][0] * 0.125f;
        o.y = pv[d0][1] * 0.125f;
        o.z = pv[d0][2] * 0.125f;
        o.w = pv[d0][3] * 0.125f;
        *reinterpret_cast<float4*>(Of + (size_t)(row0w + lm) * DHEAD + d0 * 16 + lk * 4) = o;
    }
    #undef SCORE_TILE
}

extern "C" void kernel_launch(void* const* d_in, const int* in_sizes, int n_in,
                              void* d_out, int out_size, void* d_ws, size_t ws_size,
                              hipStream_t stream) {
    const float* q = (const float*)d_in[0];
    const float* k = (const float*)d_in[1];
    const float* v = (const float*)d_in[2];
    float* out = (float*)d_out;

    const int nElem = in_sizes[0];                    // B*H*S*D = 4194304
    const int BH    = nElem / (S_LEN * DHEAD);

    unsigned short* ks  = (unsigned short*)d_ws;
    unsigned short* vts = ks + nElem;

    const int nfrag = nElem / 8;                      // 524288 fragments each
    kswz_kernel<<<(nfrag + 255) / 256, 256, 0, stream>>>(k, (uint4*)ks, nfrag);
    vtswz_kernel<<<(nfrag + 255) / 256, 256, 0, stream>>>(v, (uint4*)vts, nfrag);
    const int grid = BH * (S_LEN / (WROWS * BWAVES)); // 1024 blocks
    spx_main<<<grid, 256, 0, stream>>>(q, ks, vts, out);
}